// Round 10
// baseline (130.300 us; speedup 1.0000x reference)
//
#include <hip/hip_runtime.h>
#include <math.h>

// MultiInterestExtractor — round 10: persistent blocks + cross-sample prefetch.
// r9 post-mortem: still latency/duty-bound (58.8us vs 35us HBM demand, ~60%
// duty); occupancy saturated. This round makes the HBM stream continuous:
//  * 1024 persistent blocks (4/CU, all resident), dynamic work-stealing via
//    an atomic counter in d_ws (memsetAsync-reset each launch) — keeps the
//    dynamic balance that static striding would lose (slen-variance tail).
//  * software pipeline across SAMPLES: while computing sample n from LDS,
//    the 13 clamped float4 loads of sample nn are in flight into registers.
//  * raw s_barrier + lgkmcnt(0)-only drains (8-phase-template pattern): the
//    prefetch loads stay in flight across both block syncs (__syncthreads
//    would drain vmcnt(0) and serialize — the m97 stall).
// Body per sample = r9: bf16-h LDS (XOR-swizzled uint2 slots), blocked
// row->wave mapping (work ∝ slen), fixed-shift softmax (e = exp(s-B_k),
// hard bound, tanh in [-1,1]), plain-sum merge in the wave's dead h region.

#define LL 200
#define DD 64
#define AA 5
#define KK 4
#define RPW 50             // rows per wave (blocked)
#define WU2 832            // uint2 slots per wave region (52 rows x 16)
#define FREG (WU2 * 2)     // floats per region as merge scratch

__device__ __forceinline__ unsigned bf16_rne(float f) {   // finite inputs
    unsigned u = __float_as_uint(f);
    return (u + 0x7FFFu + ((u >> 16) & 1u)) >> 16;
}
__device__ __forceinline__ unsigned pk2(float lo, float hi) {
    return bf16_rne(lo) | (bf16_rne(hi) << 16);
}
__device__ __forceinline__ float lo16(unsigned u) { return __uint_as_float(u << 16); }
__device__ __forceinline__ float hi16(unsigned u) { return __uint_as_float(u & 0xFFFF0000u); }

__device__ __forceinline__ float fast_tanh(float x) {
    float e = __expf(2.f * x);                          // +inf for large x ok
    return 1.f - 2.f * __builtin_amdgcn_rcpf(e + 1.f);  // saturates to +/-1
}

__global__ __launch_bounds__(256, 4)
void mie_fused(const float* __restrict__ h_g,    // [N, L, D]
               const int*   __restrict__ slen_g, // [N]
               const float* __restrict__ W1w,    // [A, D]
               const float* __restrict__ W1b,    // [A]
               const float* __restrict__ W2w,    // [K, A]
               const float* __restrict__ W2b,    // [K]
               float*       __restrict__ out,    // [N, K, D]
               int*         __restrict__ ctr,    // work-steal counter (ws)
               int N)
{
    __shared__ uint2  hbuf[4 * WU2];        // 26624 B (bf16 h, 4 wave regions)
    __shared__ float4 p4s[4][52];           //  3328 B per-row e[k]
    __shared__ float  den_s[4][4][KK];      //   256 B [wave][rq][k]
    __shared__ int    nxt_s;                // next stolen sample index

    const int t    = threadIdx.x;
    const int w    = t >> 6;
    const int lane = t & 63;
    uint2* hbw     = &hbuf[w * WU2];
    float* fregion = (float*)hbw;           // merge scratch (h dead by then)
    const float4* W14 = (const float4*)W1w;
    const int base = w * RPW * 16;          // first f4 of wave's row span
    const int G    = gridDim.x;

    // hard per-head score bound (tanh in [-1,1]): shift shared everywhere
    float Bk[KK];
    #pragma unroll
    for (int k = 0; k < KK; ++k) {
        float b = fabsf(W2b[k]);
        #pragma unroll
        for (int a = 0; a < AA; ++a) b += fabsf(W2w[k * AA + a]);
        Bk[k] = b;
    }

    // ---- prologue: sample n0 = bid; issue its loads; steal nn ----
    int n     = blockIdx.x;                 // grid <= N, always valid
    int slen  = slen_g[n];
    int nrows = min(max(slen - w * RPW, 0), RPW);
    float4 rn[13];
    if (nrows > 0) {
        const float4* hp = (const float4*)(h_g + (size_t)n * (LL * DD));
        const int nf4 = slen * 16;
        #pragma unroll
        for (int j = 0; j < 13; ++j)
            rn[j] = hp[min(base + j * 64 + lane, nf4 - 1)];  // clamp: L2 dup
    }
    if (t == 0) nxt_s = G + atomicAdd(ctr, 1);
    asm volatile("s_waitcnt lgkmcnt(0)" ::: "memory");
    __builtin_amdgcn_s_barrier();           // publish nxt_s; loads in flight
    int nn = __builtin_amdgcn_readfirstlane(nxt_s);

    while (true) {
        const int jmax = (nrows + 3) >> 2;  // 0..13 row-groups this wave

        // ---- pack current rn -> LDS (active) or zero merge region (idle) ----
        if (nrows == 0) {
            float4 z = {0.f, 0.f, 0.f, 0.f};
            #pragma unroll
            for (int q = 0; q < 4; ++q)
                *(float4*)&fregion[q * 256 + lane * 4] = z;
            if (lane < 4) *(float4*)&den_s[w][lane][0] = z;
        } else {
            #pragma unroll
            for (int j = 0; j < 13; ++j)
                if (j < jmax) {             // uniform branch
                    int i = j * 64 + lane;
                    int r = i >> 4, c = i & 15;
                    hbw[r * 16 + (c ^ (r & 15))] =
                        make_uint2(pk2(rn[j].x, rn[j].y), pk2(rn[j].z, rn[j].w));
                }
        }

        // ---- issue NEXT sample's loads (overlap with all compute below) ----
        int slen_n = 0, nrows_n = 0;
        if (nn < N) {
            slen_n  = slen_g[nn];           // nn uniform -> scalar load
            nrows_n = min(max(slen_n - w * RPW, 0), RPW);
            if (nrows_n > 0) {
                const float4* hp = (const float4*)(h_g + (size_t)nn * (LL * DD));
                const int nf4 = slen_n * 16;
                #pragma unroll
                for (int j = 0; j < 13; ++j)
                    rn[j] = hp[min(base + j * 64 + lane, nf4 - 1)];
            }
        }
        if (t == 0) nxt_s = G + atomicAdd(ctr, 1);   // steal next-next

        // ---- compute current sample from LDS ----
        if (nrows > 0) {
            asm volatile("s_waitcnt lgkmcnt(0)" ::: "memory");  // pack visible

            // scores: lane = local row (clamped dup); W1 wave-uniform
            const int rl = min(lane, nrows - 1);
            float a0 = W1b[0], a1 = W1b[1], a2 = W1b[2], a3 = W1b[3], a4 = W1b[4];
            #pragma unroll
            for (int i = 0; i < 16; ++i) {
                uint2 q = hbw[rl * 16 + (i ^ (rl & 15))];
                float hx = lo16(q.x), hy = hi16(q.x), hz = lo16(q.y), hw = hi16(q.y);
                float4 w0 = W14[0*16+i], w1 = W14[1*16+i], w2 = W14[2*16+i],
                       w3 = W14[3*16+i], w4 = W14[4*16+i];
                a0 = fmaf(hx, w0.x, fmaf(hy, w0.y, fmaf(hz, w0.z, fmaf(hw, w0.w, a0))));
                a1 = fmaf(hx, w1.x, fmaf(hy, w1.y, fmaf(hz, w1.z, fmaf(hw, w1.w, a1))));
                a2 = fmaf(hx, w2.x, fmaf(hy, w2.y, fmaf(hz, w2.z, fmaf(hw, w2.w, a2))));
                a3 = fmaf(hx, w3.x, fmaf(hy, w3.y, fmaf(hz, w3.z, fmaf(hw, w3.w, a3))));
                a4 = fmaf(hx, w4.x, fmaf(hy, w4.y, fmaf(hz, w4.z, fmaf(hw, w4.w, a4))));
            }
            const bool vrow = lane < nrows;
            const float t0 = fast_tanh(a0), t1 = fast_tanh(a1), t2 = fast_tanh(a2),
                        t3 = fast_tanh(a3), t4 = fast_tanh(a4);
            float e[KK];
            #pragma unroll
            for (int k = 0; k < KK; ++k) {
                float s = W2b[k];
                s = fmaf(t0, W2w[k*AA+0], s);
                s = fmaf(t1, W2w[k*AA+1], s);
                s = fmaf(t2, W2w[k*AA+2], s);
                s = fmaf(t3, W2w[k*AA+3], s);
                s = fmaf(t4, W2w[k*AA+4], s);
                e[k] = vrow ? __expf(s - Bk[k]) : 0.f;        // e in (0,1]
            }
            if (lane < 52)
                p4s[w][lane] = make_float4(e[0], e[1], e[2], e[3]); // pads: 0

            asm volatile("s_waitcnt lgkmcnt(0)" ::: "memory");

            // PV: lane = (rq = lane>>4 row-in-group, dc = lane&15 slot)
            const int rq = lane >> 4, dc = lane & 15;
            float4 acc0 = {0,0,0,0}, acc1 = {0,0,0,0},
                   acc2 = {0,0,0,0}, acc3 = {0,0,0,0};
            float dn0 = 0.f, dn1 = 0.f, dn2 = 0.f, dn3 = 0.f;
            for (int g = 0; g < jmax; ++g) {
                const int row = g * 4 + rq;                   // pads have e=0
                uint2 q = hbw[row * 16 + (dc ^ (row & 15))];
                float hx = lo16(q.x), hy = hi16(q.x), hz = lo16(q.y), hw = hi16(q.y);
                float4 pv = p4s[w][row];
                acc0.x = fmaf(pv.x, hx, acc0.x); acc0.y = fmaf(pv.x, hy, acc0.y);
                acc0.z = fmaf(pv.x, hz, acc0.z); acc0.w = fmaf(pv.x, hw, acc0.w);
                acc1.x = fmaf(pv.y, hx, acc1.x); acc1.y = fmaf(pv.y, hy, acc1.y);
                acc1.z = fmaf(pv.y, hz, acc1.z); acc1.w = fmaf(pv.y, hw, acc1.w);
                acc2.x = fmaf(pv.z, hx, acc2.x); acc2.y = fmaf(pv.z, hy, acc2.y);
                acc2.z = fmaf(pv.z, hz, acc2.z); acc2.w = fmaf(pv.z, hw, acc2.w);
                acc3.x = fmaf(pv.w, hx, acc3.x); acc3.y = fmaf(pv.w, hy, acc3.y);
                acc3.z = fmaf(pv.w, hz, acc3.z); acc3.w = fmaf(pv.w, hw, acc3.w);
                dn0 += pv.x; dn1 += pv.y; dn2 += pv.z; dn3 += pv.w;
            }

            // merge: rq-partials into OWN dead h region (no shuffles)
            *(float4*)&fregion[rq * 256 + 0 * 64 + dc * 4] = acc0;
            *(float4*)&fregion[rq * 256 + 1 * 64 + dc * 4] = acc1;
            *(float4*)&fregion[rq * 256 + 2 * 64 + dc * 4] = acc2;
            *(float4*)&fregion[rq * 256 + 3 * 64 + dc * 4] = acc3;
            if (dc == 0)
                *(float4*)&den_s[w][rq][0] = make_float4(dn0, dn1, dn2, dn3);
        }

        // ---- B1: merge writes visible; prefetch loads stay in flight ----
        asm volatile("s_waitcnt lgkmcnt(0)" ::: "memory");
        __builtin_amdgcn_s_barrier();

        // ---- epilogue: sum 16 partials per output element, store out[n] ----
        {
            const float* fb = (const float*)hbuf;
            float s = 0.f;
            #pragma unroll
            for (int i = 0; i < 16; ++i)
                s += fb[(i >> 2) * FREG + (i & 3) * 256 + t];  // stride-1 in t
            const int k = t >> 6;
            float den = 0.f;
            #pragma unroll
            for (int i = 0; i < 16; ++i)
                den += den_s[i >> 2][i & 3][k];                // broadcast
            out[(size_t)n * (KK * DD) + t] = s / den;          // den>0
        }
        const int nn2 = __builtin_amdgcn_readfirstlane(nxt_s);

        // ---- B2: epilogue reads done before next iteration's LDS writes ----
        asm volatile("s_waitcnt lgkmcnt(0)" ::: "memory");
        __builtin_amdgcn_s_barrier();

        n = nn; slen = slen_n; nrows = nrows_n; nn = nn2;
        if (n >= N) break;
    }
}

extern "C" void kernel_launch(void* const* d_in, const int* in_sizes, int n_in,
                              void* d_out, int out_size, void* d_ws, size_t ws_size,
                              hipStream_t stream) {
    const float* h_g  = (const float*)d_in[0];
    const int*   slen = (const int*)  d_in[1];
    const float* W1w  = (const float*)d_in[2];
    const float* W1b  = (const float*)d_in[3];
    const float* W2w  = (const float*)d_in[4];
    const float* W2b  = (const float*)d_in[5];
    float*       outp = (float*)d_out;
    int*         ctr  = (int*)d_ws;

    const int N = in_sizes[1];
    const int grid = (N < 1024) ? N : 1024;   // 4 blocks/CU, all resident

    hipMemsetAsync(d_ws, 0, sizeof(int), stream);   // reset steal counter
    mie_fused<<<dim3(grid), dim3(256), 0, stream>>>(h_g, slen, W1w, W1b, W2w,
                                                    W2b, outp, ctr, N);
}

// Round 11
// 65.126 us; speedup vs baseline: 2.0007x; 2.0007x over previous
//
#include <hip/hip_runtime.h>
#include <math.h>

// MultiInterestExtractor — round 11: r9 base + 2-phase upfront staging.
// r10 post-mortem: persistent+steal coupled independent chains through
// barriers + a dependent slen load -> 2.2x regression; reverted.
// r9's one measurable regression vs r8: staging in groups of 4 = up to 4
// serial HBM round-trips per wave. Here: issue up to 8 loads -> write ->
// issue remaining <=5 -> write. Mean round-trips 1.8 -> 1.2, worst 4 -> 2
// (the slen=200 tail that sets block time). VGPR ~80 keeps 5 blocks/CU.
// Everything else = r9: blocked row->wave mapping (work ∝ slen), bf16-h LDS
// (XOR-swizzled uint2 slots), fixed-shift softmax (e = exp(s-B_k), hard
// bound, tanh in [-1,1]), plain-sum merge in the wave's dead h region.

#define LL 200
#define DD 64
#define AA 5
#define KK 4
#define RPW 50             // rows per wave (blocked)
#define WU2 832            // uint2 slots per wave region (52 rows x 16)
#define FREG (WU2 * 2)     // floats per region as merge scratch

__device__ __forceinline__ unsigned bf16_rne(float f) {   // finite inputs
    unsigned u = __float_as_uint(f);
    return (u + 0x7FFFu + ((u >> 16) & 1u)) >> 16;
}
__device__ __forceinline__ unsigned pk2(float lo, float hi) {
    return bf16_rne(lo) | (bf16_rne(hi) << 16);
}
__device__ __forceinline__ float lo16(unsigned u) { return __uint_as_float(u << 16); }
__device__ __forceinline__ float hi16(unsigned u) { return __uint_as_float(u & 0xFFFF0000u); }

__device__ __forceinline__ float fast_tanh(float x) {
    float e = __expf(2.f * x);                          // +inf for large x ok
    return 1.f - 2.f * __builtin_amdgcn_rcpf(e + 1.f);  // saturates to +/-1
}

__global__ __launch_bounds__(256, 5)
void mie_fused(const float* __restrict__ h_g,    // [N, L, D]
               const int*   __restrict__ slen_g, // [N]
               const float* __restrict__ W1w,    // [A, D]
               const float* __restrict__ W1b,    // [A]
               const float* __restrict__ W2w,    // [K, A]
               const float* __restrict__ W2b,    // [K]
               float*       __restrict__ out)    // [N, K, D]
{
    __shared__ uint2  hbuf[4 * WU2];        // 26624 B (bf16 h, 4 wave regions)
    __shared__ float4 p4s[4][52];           //  3328 B per-row e[k]
    __shared__ float  den_s[4][4][KK];      //   256 B [wave][rq][k]

    const int n    = blockIdx.x;
    const int t    = threadIdx.x;
    const int w    = t >> 6;                // wave id
    const int lane = t & 63;
    const int slen = slen_g[n];

    // blocked assignment: wave w owns global rows [RPW*w, RPW*w + nrows)
    const int nrows = min(max(slen - w * RPW, 0), RPW);   // 0..50
    uint2* hbw     = &hbuf[w * WU2];
    float* fregion = (float*)hbw;           // merge scratch (h dead by then)

    if (nrows == 0) {
        // idle wave (mean 1.5 of 4): zero merge region + den, wait at barrier
        float4 z = {0.f, 0.f, 0.f, 0.f};
        #pragma unroll
        for (int q = 0; q < 4; ++q)
            *(float4*)&fregion[q * 256 + lane * 4] = z;
        if (lane < 4) *(float4*)&den_s[w][lane][0] = z;
    } else {
        const int nf4  = slen * 16;
        const float4* hn4 = (const float4*)(h_g + (size_t)n * (LL * DD));
        const int base = w * RPW * 16;              // first f4 of wave's span
        const int jmax = (nrows + 3) >> 2;          // 1..13 stage/PV groups

        // ---- stage, 2 phases: issue<=8 loads -> write; issue<=5 -> write.
        //      Each load reads a contiguous 1KB; pack bf16, XOR swizzle. ----
        float4 rn[8];
        const int jA = min(jmax, 8);
        #pragma unroll
        for (int j = 0; j < 8; ++j)
            if (j < jA)
                rn[j] = hn4[min(base + j * 64 + lane, nf4 - 1)];  // clamp dup
        #pragma unroll
        for (int j = 0; j < 8; ++j)
            if (j < jA) {
                int i = j * 64 + lane;
                int r = i >> 4, c = i & 15;
                hbw[r * 16 + (c ^ (r & 15))] =
                    make_uint2(pk2(rn[j].x, rn[j].y), pk2(rn[j].z, rn[j].w));
            }
        if (jmax > 8) {
            #pragma unroll
            for (int j = 8; j < 13; ++j)
                if (j < jmax)
                    rn[j - 8] = hn4[min(base + j * 64 + lane, nf4 - 1)];
            #pragma unroll
            for (int j = 8; j < 13; ++j)
                if (j < jmax) {
                    int i = j * 64 + lane;
                    int r = i >> 4, c = i & 15;
                    hbw[r * 16 + (c ^ (r & 15))] =
                        make_uint2(pk2(rn[j - 8].x, rn[j - 8].y),
                                   pk2(rn[j - 8].z, rn[j - 8].w));
                }
        }

        // hard per-head score bound (tanh in [-1,1]): same shift everywhere
        float Bk[KK];
        #pragma unroll
        for (int k = 0; k < KK; ++k) {
            float b = fabsf(W2b[k]);
            #pragma unroll
            for (int a = 0; a < AA; ++a) b += fabsf(W2w[k * AA + a]);
            Bk[k] = b;
        }

        asm volatile("s_waitcnt lgkmcnt(0)" ::: "memory");

        // ---- scores: lane = local row (dup-clamped to valid -> finite,
        //      broadcast reads free); W1 lane-uniform -> scalar loads ----
        const float4* W14 = (const float4*)W1w;
        const int rl = min(lane, nrows - 1);
        float a0 = W1b[0], a1 = W1b[1], a2 = W1b[2], a3 = W1b[3], a4 = W1b[4];
        #pragma unroll
        for (int i = 0; i < 16; ++i) {
            uint2 q = hbw[rl * 16 + (i ^ (rl & 15))];
            float hx = lo16(q.x), hy = hi16(q.x), hz = lo16(q.y), hw = hi16(q.y);
            float4 w0 = W14[0*16+i], w1 = W14[1*16+i], w2 = W14[2*16+i],
                   w3 = W14[3*16+i], w4 = W14[4*16+i];
            a0 = fmaf(hx, w0.x, fmaf(hy, w0.y, fmaf(hz, w0.z, fmaf(hw, w0.w, a0))));
            a1 = fmaf(hx, w1.x, fmaf(hy, w1.y, fmaf(hz, w1.z, fmaf(hw, w1.w, a1))));
            a2 = fmaf(hx, w2.x, fmaf(hy, w2.y, fmaf(hz, w2.z, fmaf(hw, w2.w, a2))));
            a3 = fmaf(hx, w3.x, fmaf(hy, w3.y, fmaf(hz, w3.z, fmaf(hw, w3.w, a3))));
            a4 = fmaf(hx, w4.x, fmaf(hy, w4.y, fmaf(hz, w4.z, fmaf(hw, w4.w, a4))));
        }
        const bool vrow = lane < nrows;
        const float t0 = fast_tanh(a0), t1 = fast_tanh(a1), t2 = fast_tanh(a2),
                    t3 = fast_tanh(a3), t4 = fast_tanh(a4);
        float e[KK];
        #pragma unroll
        for (int k = 0; k < KK; ++k) {
            float s = W2b[k];
            s = fmaf(t0, W2w[k*AA+0], s);
            s = fmaf(t1, W2w[k*AA+1], s);
            s = fmaf(t2, W2w[k*AA+2], s);
            s = fmaf(t3, W2w[k*AA+3], s);
            s = fmaf(t4, W2w[k*AA+4], s);
            e[k] = vrow ? __expf(s - Bk[k]) : 0.f;         // e in (0,1]
        }
        if (lane < 52)
            p4s[w][lane] = make_float4(e[0], e[1], e[2], e[3]); // pads: e=0

        asm volatile("s_waitcnt lgkmcnt(0)" ::: "memory");

        // ---- PV: lane = (rq = lane>>4 row-in-group, dc = lane&15 slot) ----
        const int rq = lane >> 4, dc = lane & 15;
        float4 acc0 = {0,0,0,0}, acc1 = {0,0,0,0}, acc2 = {0,0,0,0}, acc3 = {0,0,0,0};
        float dn0 = 0.f, dn1 = 0.f, dn2 = 0.f, dn3 = 0.f;
        for (int g = 0; g < jmax; ++g) {
            const int row = g * 4 + rq;                    // <= 51; pads e=0
            uint2 q = hbw[row * 16 + (dc ^ (row & 15))];
            float hx = lo16(q.x), hy = hi16(q.x), hz = lo16(q.y), hw = hi16(q.y);
            float4 pv = p4s[w][row];
            acc0.x = fmaf(pv.x, hx, acc0.x); acc0.y = fmaf(pv.x, hy, acc0.y);
            acc0.z = fmaf(pv.x, hz, acc0.z); acc0.w = fmaf(pv.x, hw, acc0.w);
            acc1.x = fmaf(pv.y, hx, acc1.x); acc1.y = fmaf(pv.y, hy, acc1.y);
            acc1.z = fmaf(pv.y, hz, acc1.z); acc1.w = fmaf(pv.y, hw, acc1.w);
            acc2.x = fmaf(pv.z, hx, acc2.x); acc2.y = fmaf(pv.z, hy, acc2.y);
            acc2.z = fmaf(pv.z, hz, acc2.z); acc2.w = fmaf(pv.z, hw, acc2.w);
            acc3.x = fmaf(pv.w, hx, acc3.x); acc3.y = fmaf(pv.w, hy, acc3.y);
            acc3.z = fmaf(pv.w, hz, acc3.z); acc3.w = fmaf(pv.w, hw, acc3.w);
            dn0 += pv.x; dn1 += pv.y; dn2 += pv.z; dn3 += pv.w;
        }

        // ---- merge: rq-partials into OWN dead h region (no shuffles) ----
        *(float4*)&fregion[rq * 256 + 0 * 64 + dc * 4] = acc0;
        *(float4*)&fregion[rq * 256 + 1 * 64 + dc * 4] = acc1;
        *(float4*)&fregion[rq * 256 + 2 * 64 + dc * 4] = acc2;
        *(float4*)&fregion[rq * 256 + 3 * 64 + dc * 4] = acc3;
        if (dc == 0)
            *(float4*)&den_s[w][rq][0] = make_float4(dn0, dn1, dn2, dn3);
    }

    __syncthreads();

    // ---- epilogue: sum 16 partials (4 waves x 4 rq) per output element ----
    {
        const float* fb = (const float*)hbuf;
        float s = 0.f;
        #pragma unroll
        for (int i = 0; i < 16; ++i)
            s += fb[(i >> 2) * FREG + (i & 3) * 256 + t];  // stride-1 in t
        const int k = t >> 6;
        float den = 0.f;
        #pragma unroll
        for (int i = 0; i < 16; ++i)
            den += den_s[i >> 2][i & 3][k];                // broadcast reads
        out[(size_t)n * (KK * DD) + t] = s / den;          // den>0 (slen>=1)
    }
}

extern "C" void kernel_launch(void* const* d_in, const int* in_sizes, int n_in,
                              void* d_out, int out_size, void* d_ws, size_t ws_size,
                              hipStream_t stream) {
    const float* h_g  = (const float*)d_in[0];
    const int*   slen = (const int*)  d_in[1];
    const float* W1w  = (const float*)d_in[2];
    const float* W1b  = (const float*)d_in[3];
    const float* W2w  = (const float*)d_in[4];
    const float* W2b  = (const float*)d_in[5];
    float*       outp = (float*)d_out;

    const int N = in_sizes[1];

    mie_fused<<<dim3(N), dim3(256), 0, stream>>>(h_g, slen, W1w, W1b, W2w, W2b, outp);
}